// Round 9
// baseline (157.746 us; speedup 1.0000x reference)
//
#include <hip/hip_runtime.h>
#include <hip/hip_bf16.h>
#include <hip/hip_fp16.h>

#define NN   102400
#define NG   64
#define NPG  1600
#define NE   1638400
#define EPG  25600
#define EPC  (EPG / 4)   // 6400 edges per chunk (hist/scatter)
#define NPB  200         // nodes per gather block (8 blocks/graph)

typedef unsigned int u32;
typedef unsigned short u16;

// ---- workspace layout (float offsets), total NE + 22*NN + 4864 ≈ 15.6 MB ----
#define OFF_EDAT  0                       // u32[NE]: (sender_local<<16) | bf16(ef)
#define OFF_SPROJ (NE)                    // __half[NN*16]: [0..8)=enc p_es+ebe, [8..16)=pes2
#define OFF_PNN   (NE + 8 * NN)           // __half[NN*16]: p_nn+ebn -> n1@hWnn^T
#define OFF_DEG   (NE + 16 * NN)          // int[NN]
#define OFF_START (NE + 17 * NN)          // int[NN]: gather segment start
#define OFF_H4C   (NE + 18 * NN)          // int[4*NN]: chunk hists -> chunk cursor bases
#define OFF_GS    (NE + 22 * NN)          // sums etc (4864 floats)
// gs offsets
#define GS_ESUM1 0     // G*8
#define GS_NSUM1 512   // G*16
#define GS_ESUM2 1536  // G*8
#define GS_NSUM2 2048  // G*16
#define GS_G1    3072  // G*4
#define GS_GPE   3328  // G*8
#define GS_GPN   3840  // G*16

struct H8 { __half2 a, b, c, d; };
struct H4 { __half2 a, b; };

__device__ __forceinline__ void unpack8(const H8 v, float* o) {
    float2 t0 = __half22float2(v.a), t1 = __half22float2(v.b);
    float2 t2 = __half22float2(v.c), t3 = __half22float2(v.d);
    o[0]=t0.x; o[1]=t0.y; o[2]=t1.x; o[3]=t1.y; o[4]=t2.x; o[5]=t2.y; o[6]=t3.x; o[7]=t3.y;
}
__device__ __forceinline__ H8 pack8(const float* v) {
    H8 r;
    r.a = __floats2half2_rn(v[0], v[1]); r.b = __floats2half2_rn(v[2], v[3]);
    r.c = __floats2half2_rn(v[4], v[5]); r.d = __floats2half2_rn(v[6], v[7]);
    return r;
}
__device__ __forceinline__ H4 pack4(const float* v) {
    H4 r;
    r.a = __floats2half2_rn(v[0], v[1]); r.b = __floats2half2_rn(v[2], v[3]);
    return r;
}
__device__ __forceinline__ u16 f2bf(float f) {
    u32 u = __float_as_uint(f);
    return (u16)((u + 0x7fffu + ((u >> 16) & 1u)) >> 16);
}
// sum over the 32 lanes of the same parity class (strides 2..32 preserve parity)
__device__ __forceinline__ float wsum_par(float v) {
#pragma unroll
    for (int o = 2; o <= 32; o <<= 1) v += __shfl_xor(v, o);
    return v;
}
__device__ __forceinline__ float sigmoidf_(float x) { return 1.f / (1.f + expf(-x)); }

// H1: per-chunk receiver histogram (LDS atomics only), plain stores to h4.
__global__ __launch_bounds__(512) void k_hist4(const int* __restrict__ rcv, int* __restrict__ h4) {
    __shared__ int h[NPG];
    const int g = blockIdx.x >> 2, c = blockIdx.x & 3;
    for (int i = threadIdx.x; i < NPG; i += 512) h[i] = 0;
    __syncthreads();
    const int base = g * EPG + c * EPC;
    for (int t = threadIdx.x; t < EPC; t += 512) atomicAdd(&h[rcv[base + t] - g * NPG], 1);
    __syncthreads();
    int* out = h4 + (size_t)(g * 4 + c) * NPG;
    for (int i = threadIdx.x; i < NPG; i += 512) out[i] = h[i];
}

// H2: per-graph scan: deg, start, and in-place chunk cursor bases in h4c.
__global__ __launch_bounds__(320) void k_scan(
    int* __restrict__ h4c, int* __restrict__ deg, int* __restrict__ start)
{
    __shared__ int part[320];
    const int g = blockIdx.x, tid = threadIdx.x;
    const int vb = tid * 5;
    int hc[5][4], d[5], pre[5];
    int ts = 0;
#pragma unroll
    for (int i = 0; i < 5; ++i) {
        const int v = vb + i;
#pragma unroll
        for (int c = 0; c < 4; ++c) hc[i][c] = h4c[(size_t)(g * 4 + c) * NPG + v];
        d[i] = hc[i][0] + hc[i][1] + hc[i][2] + hc[i][3];
        pre[i] = ts;
        ts += d[i];
    }
    part[tid] = ts;
    __syncthreads();
    for (int o = 1; o < 320; o <<= 1) {
        const int v = (tid >= o) ? part[tid - o] : 0;
        __syncthreads();
        part[tid] += v;
        __syncthreads();
    }
    const int off = g * EPG + part[tid] - ts;
#pragma unroll
    for (int i = 0; i < 5; ++i) {
        const int v = vb + i;
        const int st = off + pre[i];
        deg[g * NPG + v] = d[i];
        start[g * NPG + v] = st;
        int run = st;
#pragma unroll
        for (int c = 0; c < 4; ++c) {
            h4c[(size_t)(g * 4 + c) * NPG + v] = run;
            run += hc[i][c];
        }
    }
}

// H3: scatter edges into receiver-sorted order via LDS cursors (no global atomics).
__global__ __launch_bounds__(512) void k_scatter4(
    const float* __restrict__ ef, const int* __restrict__ snd, const int* __restrict__ rcv,
    const int* __restrict__ h4c, u32* __restrict__ edat)
{
    __shared__ int cur[NPG];
    const int g = blockIdx.x >> 2, c = blockIdx.x & 3;
    const int* cb = h4c + (size_t)(g * 4 + c) * NPG;
    for (int i = threadIdx.x; i < NPG; i += 512) cur[i] = cb[i];
    __syncthreads();
    const int base = g * EPG + c * EPC;
    for (int t = threadIdx.x; t < EPC; t += 512) {
        const int e = base + t;
        const int r = rcv[e] - g * NPG;
        const int p = atomicAdd(&cur[r], 1);
        const u32 s = (u32)(snd[e] - g * NPG);
        edat[p] = (s << 16) | (u32)f2bf(ef[e]);
    }
}

// K1: per-node encoder pre-projections (f32 in, f16 out); biases folded; also zeros gs.
__global__ __launch_bounds__(256) void k_node_pre(
    const float* __restrict__ nf,
    const float* __restrict__ Wes,   // [8][60]
    const float* __restrict__ Wnn,   // [16][60]
    const float* __restrict__ ebe, const float* __restrict__ ebn,
    __half* __restrict__ sproj, __half* __restrict__ pnn, float* __restrict__ gs)
{
    __shared__ float wE[480], wN[960];
    for (int i = threadIdx.x; i < 480; i += 256) wE[i] = Wes[i];
    for (int i = threadIdx.x; i < 960; i += 256) wN[i] = Wnn[i];
    if (blockIdx.x == 0) {
        for (int i = threadIdx.x; i < 3072; i += 256) gs[i] = 0.f;
    }
    __syncthreads();
    const int v = blockIdx.x * 256 + threadIdx.x;
    const float4* row = reinterpret_cast<const float4*>(nf + (size_t)v * 60);
    float x[60];
#pragma unroll
    for (int i = 0; i < 15; ++i) {
        const float4 a = row[i];
        x[4 * i] = a.x; x[4 * i + 1] = a.y; x[4 * i + 2] = a.z; x[4 * i + 3] = a.w;
    }
    float pes[8], pn[16];
#pragma unroll
    for (int j = 0; j < 8; ++j) pes[j] = ebe[j];
#pragma unroll
    for (int j = 0; j < 16; ++j) pn[j] = ebn[j];
#pragma unroll
    for (int k = 0; k < 60; ++k) {
        const float xv = x[k];
#pragma unroll
        for (int j = 0; j < 8; ++j)  pes[j] = fmaf(xv, wE[j * 60 + k], pes[j]);
#pragma unroll
        for (int j = 0; j < 16; ++j) pn[j]  = fmaf(xv, wN[j * 60 + k], pn[j]);
    }
    H8* sp = reinterpret_cast<H8*>(sproj) + (size_t)v * 2;
    sp[0] = pack8(pes);
    H8* pp = reinterpret_cast<H8*>(pnn) + (size_t)v * 2;
    pp[0] = pack8(pn); pp[1] = pack8(pn + 8);
}

// K2: encoder edge gather (LDS-staged sproj A) + node layer; 8 blocks/graph, 2 thr/node.
__global__ __launch_bounds__(512) void k_enc(
    const int* __restrict__ deg, const int* __restrict__ start, const u32* __restrict__ edat,
    __half* __restrict__ sproj, __half* __restrict__ pnn,
    const float* __restrict__ eWee,
    const float* __restrict__ eWni,
    const float* __restrict__ hWes, const float* __restrict__ hWnn,
    float* __restrict__ esum, float* __restrict__ nsum)
{
    __shared__ float4 sA[NPG];               // 25.6 KB: A halves of this graph's sproj
    __shared__ float wNI[128], wES[128], wNN2[256];
    const int g = blockIdx.x >> 3, c = blockIdx.x & 7;
    const int tid = threadIdx.x;
    const float4* f4sp = reinterpret_cast<const float4*>(sproj);
    for (int i = tid; i < NPG; i += 512) sA[i] = f4sp[(size_t)(g * NPG + i) * 2];
    for (int i = tid; i < 128; i += 512) { wNI[i] = eWni[i]; wES[i] = hWes[i]; }
    for (int i = tid; i < 256; i += 512) wNN2[i] = hWnn[i];
    __syncthreads();
    float wee[8];
#pragma unroll
    for (int j = 0; j < 8; ++j) wee[j] = eWee[j];
    const int local = tid >> 1, h = tid & 1;
    const bool act = local < NPB;
    const int v = g * NPG + c * NPB + (act ? local : 0);
    const int dg = act ? deg[v] : 0;
    const int st = act ? start[v] : 0;
    const int half0 = dg >> 1;
    int i = st + (h ? half0 : 0);
    const int iend = st + (h ? dg : half0);
    float m[8];
#pragma unroll
    for (int j = 0; j < 8; ++j) m[j] = 0.f;
    const H8* hb = reinterpret_cast<const H8*>(sA);

#define ENC_EDGE(W, A) { \
    const float f_ = __uint_as_float(((W) & 0xffffu) << 16); \
    float pv_[8]; unpack8((A), pv_); \
    _Pragma("unroll") \
    for (int j = 0; j < 8; ++j) m[j] += fmaxf(0.f, fmaf(f_, wee[j], pv_[j])); }

    for (; i + 4 <= iend; i += 4) {
        const u32 w0 = edat[i], w1 = edat[i + 1], w2v = edat[i + 2], w3v = edat[i + 3];
        const H8 A0 = hb[w0 >> 16];
        const H8 A1 = hb[w1 >> 16];
        const H8 A2 = hb[w2v >> 16];
        const H8 A3 = hb[w3v >> 16];
        ENC_EDGE(w0, A0) ENC_EDGE(w1, A1) ENC_EDGE(w2v, A2) ENC_EDGE(w3v, A3)
    }
    for (; i < iend; ++i) {
        const u32 w = edat[i];
        const H8 A = hb[w >> 16];
        ENC_EDGE(w, A)
    }
#undef ENC_EDGE

    // pair combine -> both lanes hold full segment sum
#pragma unroll
    for (int j = 0; j < 8; ++j) m[j] += __shfl_xor(m[j], 1);
#pragma unroll
    for (int j = 0; j < 8; ++j) {
        const float s = wsum_par(m[j]);
        if ((tid & 63) == 0) atomicAdd(&esum[g * 8 + j], s);
    }
    const float ic = 1.f / fmaxf((float)dg, 1.f);
    float mk[8];
#pragma unroll
    for (int k = 0; k < 8; ++k) mk[k] = m[k] * ic;
    // node layer: own j-half (inactive lanes: pn8=0, mk=0 -> n1=0)
    float pn8[8];
    if (act) {
        const H8* pp = reinterpret_cast<const H8*>(pnn) + (size_t)v * 2;
        unpack8(pp[h], pn8);
    } else {
#pragma unroll
        for (int jj = 0; jj < 8; ++jj) pn8[jj] = 0.f;
    }
    float n1[8];
#pragma unroll
    for (int jj = 0; jj < 8; ++jj) {
        float x = pn8[jj];
#pragma unroll
        for (int k = 0; k < 8; ++k) x = fmaf(mk[k], wNI[(h * 8 + jj) * 8 + k], x);
        n1[jj] = fmaxf(0.f, x);
    }
    // exchange halves -> full n1[16]
    float n1o[8];
#pragma unroll
    for (int jj = 0; jj < 8; ++jj) n1o[jj] = __shfl_xor(n1[jj], 1);
    float full[16];
#pragma unroll
    for (int jj = 0; jj < 8; ++jj) {
        full[jj]     = h ? n1o[jj] : n1[jj];
        full[8 + jj] = h ? n1[jj]  : n1o[jj];
    }
    // pe: 4 outputs per lane
    float pe4[4];
#pragma unroll
    for (int oo = 0; oo < 4; ++oo) {
        const int o = h * 4 + oo;
        float x = 0.f;
#pragma unroll
        for (int j = 0; j < 16; ++j) x = fmaf(full[j], wES[o * 16 + j], x);
        pe4[oo] = x;
    }
    if (act) *reinterpret_cast<H4*>(sproj + (size_t)v * 16 + 8 + h * 4) = pack4(pe4);
    // pw: 8 outputs per lane
    float pw8[8];
#pragma unroll
    for (int oo = 0; oo < 8; ++oo) {
        const int o = h * 8 + oo;
        float x = 0.f;
#pragma unroll
        for (int j = 0; j < 16; ++j) x = fmaf(full[j], wNN2[o * 16 + j], x);
        pw8[oo] = x;
    }
    if (act) reinterpret_cast<H8*>(pnn)[(size_t)v * 2 + h] = pack8(pw8);
    // nsum: own-half, parity-class reduce (inactive n1 are zero)
#pragma unroll
    for (int jj = 0; jj < 8; ++jj) {
        const float s = wsum_par(n1[jj]);
        if ((tid & 63) == h) atomicAdd(&nsum[g * 16 + h * 8 + jj], s);
    }
}

// K3: encoder global layer + g1 projections for hidden layers.
__global__ void k_glob_enc(
    const float* __restrict__ esum1, const float* __restrict__ nsum1,
    const float* __restrict__ Wge, const float* __restrict__ Wgn, const float* __restrict__ bg,
    const float* __restrict__ hWeg, const float* __restrict__ hWng,
    float* __restrict__ g1, float* __restrict__ gpe, float* __restrict__ gpn)
{
    const int g = threadIdx.x;
    if (g >= NG) return;
    float gv[4];
#pragma unroll
    for (int o = 0; o < 4; ++o) {
        float x = bg[o];
#pragma unroll
        for (int k = 0; k < 8; ++k)  x = fmaf(esum1[g * 8 + k] * (1.f / EPG), Wge[o * 8 + k], x);
#pragma unroll
        for (int k = 0; k < 16; ++k) x = fmaf(nsum1[g * 16 + k] * (1.f / NPG), Wgn[o * 16 + k], x);
        gv[o] = fmaxf(0.f, x);
        g1[g * 4 + o] = gv[o];
    }
#pragma unroll
    for (int j = 0; j < 8; ++j) {
        float x = 0.f;
#pragma unroll
        for (int o = 0; o < 4; ++o) x = fmaf(gv[o], hWeg[j * 4 + o], x);
        gpe[g * 8 + j] = x;
    }
#pragma unroll
    for (int j = 0; j < 16; ++j) {
        float x = 0.f;
#pragma unroll
        for (int o = 0; o < 4; ++o) x = fmaf(gv[o], hWng[j * 4 + o], x);
        gpn[g * 16 + j] = x;
    }
}

// K4: hidden edge gather (LDS-staged sproj A+B) + node layer + readout.
__global__ __launch_bounds__(512) void k_hid(
    const int* __restrict__ deg, const int* __restrict__ start, const u32* __restrict__ edat,
    const __half* __restrict__ sproj, const __half* __restrict__ pnn,
    const float* __restrict__ eWee,
    const float* __restrict__ hWee, const float* __restrict__ hbe, const float* __restrict__ gpe,
    const float* __restrict__ hWni, const float* __restrict__ hbn, const float* __restrict__ gpn,
    const float* __restrict__ roWn, const float* __restrict__ robn,
    float* __restrict__ esum, float* __restrict__ nsum, float* __restrict__ outn)
{
    __shared__ float4 sAB[NPG * 2];          // 51.2 KB: A+B halves of this graph's sproj
    __shared__ float w2[64], wNI[128], rW[16];
    const int g = blockIdx.x >> 3, c = blockIdx.x & 7;
    const int tid = threadIdx.x;
    const float4* f4sp = reinterpret_cast<const float4*>(sproj);
    for (int i = tid; i < NPG * 2; i += 512) sAB[i] = f4sp[(size_t)g * NPG * 2 + i];
    for (int i = tid; i < 128; i += 512) wNI[i] = hWni[i];
    if (tid < 64) w2[tid] = hWee[tid];
    if (tid < 16) rW[tid] = roWn[tid];
    __syncthreads();
    float wee[8], add2[8];
#pragma unroll
    for (int j = 0; j < 8; ++j) { wee[j] = eWee[j]; add2[j] = gpe[g * 8 + j] + hbe[j]; }
    const int local = tid >> 1, h = tid & 1;
    const bool act = local < NPB;
    const int v = g * NPG + c * NPB + (act ? local : 0);
    const int dg = act ? deg[v] : 0;
    const int st = act ? start[v] : 0;
    const int half0 = dg >> 1;
    int i = st + (h ? half0 : 0);
    const int iend = st + (h ? dg : half0);
    float m2[8];
#pragma unroll
    for (int j = 0; j < 8; ++j) m2[j] = 0.f;
    const H8* hb = reinterpret_cast<const H8*>(sAB);

#define HID_EDGE(W, A, B) { \
    const float f_ = __uint_as_float(((W) & 0xffffu) << 16); \
    float pv_[8], qv_[8]; unpack8((A), pv_); unpack8((B), qv_); \
    float e1_[8]; \
    _Pragma("unroll") \
    for (int j = 0; j < 8; ++j) e1_[j] = fmaxf(0.f, fmaf(f_, wee[j], pv_[j])); \
    _Pragma("unroll") \
    for (int j = 0; j < 8; ++j) { \
        float x_ = qv_[j] + add2[j]; \
        _Pragma("unroll") \
        for (int k = 0; k < 8; ++k) x_ = fmaf(e1_[k], w2[j * 8 + k], x_); \
        m2[j] += fmaxf(0.f, x_); } }

    for (; i + 4 <= iend; i += 4) {
        const u32 w0 = edat[i], w1 = edat[i + 1], w2v = edat[i + 2], w3v = edat[i + 3];
        const int s0 = (int)(w0 >> 16) * 2, s1 = (int)(w1 >> 16) * 2;
        const int s2 = (int)(w2v >> 16) * 2, s3 = (int)(w3v >> 16) * 2;
        const H8 A0 = hb[s0], B0 = hb[s0 + 1];
        const H8 A1 = hb[s1], B1 = hb[s1 + 1];
        const H8 A2 = hb[s2], B2 = hb[s2 + 1];
        const H8 A3 = hb[s3], B3 = hb[s3 + 1];
        HID_EDGE(w0, A0, B0) HID_EDGE(w1, A1, B1) HID_EDGE(w2v, A2, B2) HID_EDGE(w3v, A3, B3)
    }
    for (; i < iend; ++i) {
        const u32 w = edat[i];
        const int s = (int)(w >> 16) * 2;
        const H8 A = hb[s], B = hb[s + 1];
        HID_EDGE(w, A, B)
    }
#undef HID_EDGE

#pragma unroll
    for (int j = 0; j < 8; ++j) m2[j] += __shfl_xor(m2[j], 1);
#pragma unroll
    for (int j = 0; j < 8; ++j) {
        const float s = wsum_par(m2[j]);
        if ((tid & 63) == 0) atomicAdd(&esum[g * 8 + j], s);
    }
    const float ic = 1.f / fmaxf((float)dg, 1.f);
    float mk[8];
#pragma unroll
    for (int k = 0; k < 8; ++k) mk[k] = m2[k] * ic;
    float pn8[8];
    if (act) {
        const H8* pp = reinterpret_cast<const H8*>(pnn) + (size_t)v * 2;
        unpack8(pp[h], pn8);
    } else {
#pragma unroll
        for (int jj = 0; jj < 8; ++jj) pn8[jj] = 0.f;
    }
    float zp = 0.f;
    float n2[8];
#pragma unroll
    for (int jj = 0; jj < 8; ++jj) {
        const int j = h * 8 + jj;
        float x = pn8[jj] + gpn[g * 16 + j] + hbn[j];
#pragma unroll
        for (int k = 0; k < 8; ++k) x = fmaf(mk[k], wNI[j * 8 + k], x);
        n2[jj] = act ? fmaxf(0.f, x) : 0.f;
        zp = fmaf(n2[jj], rW[j], zp);
    }
    const float z = zp + __shfl_xor(zp, 1);
    if (act && h == 0) outn[v] = sigmoidf_(z + robn[0]);
#pragma unroll
    for (int jj = 0; jj < 8; ++jj) {
        const float s = wsum_par(n2[jj]);
        if ((tid & 63) == h) atomicAdd(&nsum[g * 16 + h * 8 + jj], s);
    }
}

// K5: hidden global layer + global readout.
__global__ void k_glob_hid(
    const float* __restrict__ esum2, const float* __restrict__ nsum2, const float* __restrict__ g1,
    const float* __restrict__ hWge, const float* __restrict__ hWgn,
    const float* __restrict__ hWgg, const float* __restrict__ hbg,
    const float* __restrict__ roWg, const float* __restrict__ robg,
    float* __restrict__ outg)
{
    const int g = threadIdx.x;
    if (g >= NG) return;
    float gv[4];
#pragma unroll
    for (int o = 0; o < 4; ++o) {
        float x = hbg[o];
#pragma unroll
        for (int k = 0; k < 8; ++k)  x = fmaf(esum2[g * 8 + k] * (1.f / EPG), hWge[o * 8 + k], x);
#pragma unroll
        for (int k = 0; k < 16; ++k) x = fmaf(nsum2[g * 16 + k] * (1.f / NPG), hWgn[o * 16 + k], x);
#pragma unroll
        for (int k = 0; k < 4; ++k)  x = fmaf(g1[g * 4 + k], hWgg[o * 4 + k], x);
        gv[o] = fmaxf(0.f, x);
    }
    float z = robg[0];
#pragma unroll
    for (int o = 0; o < 4; ++o) z = fmaf(gv[o], roWg[o], z);
    outg[g] = sigmoidf_(z);
}

extern "C" void kernel_launch(void* const* d_in, const int* in_sizes, int n_in,
                              void* d_out, int out_size, void* d_ws, size_t ws_size,
                              hipStream_t stream)
{
    const float* nf   = (const float*)d_in[0];
    const float* ef   = (const float*)d_in[1];
    const int*   snd  = (const int*)d_in[2];
    const int*   rcv  = (const int*)d_in[3];
    const float* eWee = (const float*)d_in[6];
    const float* eWes = (const float*)d_in[7];
    const float* ebe  = (const float*)d_in[8];
    const float* eWnn = (const float*)d_in[9];
    const float* eWni = (const float*)d_in[10];
    const float* ebn  = (const float*)d_in[11];
    const float* eWge = (const float*)d_in[12];
    const float* eWgn = (const float*)d_in[13];
    const float* ebg  = (const float*)d_in[14];
    const float* hWee = (const float*)d_in[15];
    const float* hWes = (const float*)d_in[16];
    const float* hWeg = (const float*)d_in[17];
    const float* hbe  = (const float*)d_in[18];
    const float* hWnn = (const float*)d_in[19];
    const float* hWni = (const float*)d_in[20];
    const float* hWng = (const float*)d_in[21];
    const float* hbn  = (const float*)d_in[22];
    const float* hWge = (const float*)d_in[23];
    const float* hWgn = (const float*)d_in[24];
    const float* hWgg = (const float*)d_in[25];
    const float* hbg  = (const float*)d_in[26];
    const float* roWn = (const float*)d_in[27];
    const float* robn = (const float*)d_in[28];
    const float* roWg = (const float*)d_in[29];
    const float* robg = (const float*)d_in[30];

    float*  ws    = (float*)d_ws;
    u32*    edat  = (u32*)(ws + OFF_EDAT);
    __half* sproj = (__half*)(ws + OFF_SPROJ);
    __half* pnn   = (__half*)(ws + OFF_PNN);
    int*    deg   = (int*)(ws + OFF_DEG);
    int*    start = (int*)(ws + OFF_START);
    int*    h4c   = (int*)(ws + OFF_H4C);
    float*  gs    = ws + OFF_GS;
    float* esum1 = gs + GS_ESUM1;
    float* nsum1 = gs + GS_NSUM1;
    float* esum2 = gs + GS_ESUM2;
    float* nsum2 = gs + GS_NSUM2;
    float* g1    = gs + GS_G1;
    float* gpe   = gs + GS_GPE;
    float* gpn   = gs + GS_GPN;
    float* out   = (float*)d_out;

    k_hist4<<<NG * 4, 512, 0, stream>>>(rcv, h4c);
    k_scan<<<NG, 320, 0, stream>>>(h4c, deg, start);
    k_scatter4<<<NG * 4, 512, 0, stream>>>(ef, snd, rcv, h4c, edat);
    k_node_pre<<<NN / 256, 256, 0, stream>>>(nf, eWes, eWnn, ebe, ebn, sproj, pnn, gs);
    k_enc<<<NG * 8, 512, 0, stream>>>(deg, start, edat, sproj, pnn,
                                      eWee, eWni, hWes, hWnn, esum1, nsum1);
    k_glob_enc<<<1, 64, 0, stream>>>(esum1, nsum1, eWge, eWgn, ebg, hWeg, hWng, g1, gpe, gpn);
    k_hid<<<NG * 8, 512, 0, stream>>>(deg, start, edat, sproj, pnn,
                                      eWee, hWee, hbe, gpe, hWni, hbn, gpn,
                                      roWn, robn, esum2, nsum2, out);
    k_glob_hid<<<1, 64, 0, stream>>>(esum2, nsum2, g1, hWge, hWgn, hWgg, hbg, roWg, robg, out + NN);
}